// Round 14
// baseline (212.169 us; speedup 1.0000x reference)
//
#include <hip/hip_runtime.h>
#include <hip/hip_fp16.h>
#include <cstdint>
#include <cmath>

#define QP    127.0f
#define MINR  1e-6f

// Problem dims: B*N = 8192 tokens, D = 1024, H = 4096
#define MTOK 8192
#define DDIM 1024
#define HDIM 4096

typedef __attribute__((ext_vector_type(4))) int int32x4;
typedef __attribute__((ext_vector_type(8))) short short8;

__global__ void zero_scales_kernel(float* g) {
    if (threadIdx.x < 4) g[threadIdx.x] = 0.0f;
}

// ---- fused 3-tensor absmax: block-range partition, atomicMax per tensor ----
__device__ __forceinline__ float wave_block_max(float m) {
    #pragma unroll
    for (int off = 32; off; off >>= 1) m = fmaxf(m, __shfl_down(m, off));
    __shared__ float sm[4];
    int lane = threadIdx.x & 63, w = threadIdx.x >> 6;
    if (lane == 0) sm[w] = m;
    __syncthreads();
    float bm = 0.0f;
    if (threadIdx.x == 0) bm = fmaxf(fmaxf(sm[0], sm[1]), fmaxf(sm[2], sm[3]));
    return bm;
}

__device__ __forceinline__ void absmax_range(const float4* in4, int n4, int bid, int nb,
                                             float* gout) {
    int tid = bid * blockDim.x + threadIdx.x;
    int stride = nb * blockDim.x;
    float m = 0.0f;
    for (int i = tid; i < n4; i += stride) {
        float4 v = in4[i];
        m = fmaxf(m, fmaxf(fmaxf(fabsf(v.x), fabsf(v.y)), fmaxf(fabsf(v.z), fabsf(v.w))));
    }
    float bm = wave_block_max(m);
    if (threadIdx.x == 0) atomicMax((int*)gout, __float_as_int(bm));
}

// blocks [0,1024) -> x, [1024,1536) -> w1, [1536,2048) -> w2
__global__ void absmax3_kernel(const float* __restrict__ x, const float* __restrict__ w1,
                               const float* __restrict__ w2, float* __restrict__ gmax) {
    int b = blockIdx.x;
    if (b < 1024)      absmax_range((const float4*)x,  MTOK * DDIM / 4, b,        1024, gmax + 0);
    else if (b < 1536) absmax_range((const float4*)w1, HDIM * DDIM / 4, b - 1024,  512, gmax + 1);
    else               absmax_range((const float4*)w2, DDIM * HDIM / 4, b - 1536,  512, gmax + 3);
}

__device__ __forceinline__ void quant_range(const float4* in4, int* out4, int n4,
                                            int bid, int nb, const float* gm) {
    const float s = fmaxf(*gm, MINR) / QP;
    int tid = bid * blockDim.x + threadIdx.x;
    int stride = nb * blockDim.x;
    for (int i = tid; i < n4; i += stride) {
        float4 v = in4[i];
        int q0 = ((int)rintf(v.x / s)) & 255;
        int q1 = ((int)rintf(v.y / s)) & 255;
        int q2 = ((int)rintf(v.z / s)) & 255;
        int q3 = ((int)rintf(v.w / s)) & 255;
        out4[i] = q0 | (q1 << 8) | (q2 << 16) | (q3 << 24);
    }
}

// blocks [0,2048) -> x, [2048,3072) -> w1, [3072,4096) -> w2
__global__ void quant3_kernel(const float* __restrict__ x, const float* __restrict__ w1,
                              const float* __restrict__ w2, int8_t* __restrict__ xq,
                              int8_t* __restrict__ w1q, int8_t* __restrict__ w2q,
                              const float* __restrict__ gmax) {
    int b = blockIdx.x;
    if (b < 2048)      quant_range((const float4*)x,  (int*)xq,  MTOK * DDIM / 4, b,        2048, gmax + 0);
    else if (b < 3072) quant_range((const float4*)w1, (int*)w1q, HDIM * DDIM / 4, b - 2048, 1024, gmax + 1);
    else               quant_range((const float4*)w2, (int*)w2q, DDIM * HDIM / 4, b - 3072, 1024, gmax + 3);
}

// quantize h (fp16) -> int8.  8 halves per thread-iter (16B loads, 8B stores).
__global__ void quant_h_kernel(const __half* __restrict__ h, int8_t* __restrict__ hq,
                               const float* __restrict__ gm) {
    const float s = fmaxf(*gm, MINR) / QP;
    const short8* in8 = (const short8*)h;
    int2* out8 = (int2*)hq;
    const int n8 = MTOK * HDIM / 8;
    int tid = blockIdx.x * blockDim.x + threadIdx.x;
    int stride = gridDim.x * blockDim.x;
    for (int i = tid; i < n8; i += stride) {
        short8 v = in8[i];
        int q[8];
        #pragma unroll
        for (int j = 0; j < 8; ++j) {
            __half_raw r; r.x = (unsigned short)v[j];
            float f = __half2float(__half(r));
            q[j] = ((int)rintf(f / s)) & 255;
        }
        int2 o;
        o.x = q[0] | (q[1] << 8) | (q[2] << 16) | (q[3] << 24);
        o.y = q[4] | (q[5] << 8) | (q[6] << 16) | (q[7] << 24);
        out8[i] = o;
    }
}

// ---------------------------------------------------------------------------
// Round-14: REG-STAGED double-buffered GEMM (T14 path).
// Motivation: 9 configs show global_load_lds caps at ~10 B/cyc/CU on this
// workload regardless of schedule/residency, while R5's plain global_load-to-
// registers path measured ~14.5 B/cyc/CU.  Staging here is:
//   issue 8 coalesced global_load_dwordx4 (next K-tile, LINEAR lane order)
//   -> compute current LDS buffer (R7's verified swizzled reads, 0 conflicts)
//   -> ds_write next buffer at SWIZZLED addresses (linear global + swizzled
//      write replaces gload_lds's pre-swizzled source; G21 satisfied since
//      write and read use the same involution)
//   -> one __syncthreads per step (its vmcnt/lgkm drain is ~free: loads were
//      consumed by the writes, writes must drain anyway).
// L2 latency (~300 cyc) hides under the ~650-cyc MFMA cluster.  LDS 64 KB ->
// 2 blocks/CU (R7's effective residency).  Write-side ~8-way bank aliasing
// accepted (~64 cyc/step/wave); reads stay conflict-free.
// ---------------------------------------------------------------------------
template<int KD, int ND, bool GELU_EPI, typename OUTT>
__global__ __launch_bounds__(256, 2)
void gemm_rs_kernel(const int8_t* __restrict__ A, const int8_t* __restrict__ B,
                    const float* __restrict__ bias,
                    const float* __restrict__ gmA, const float* __restrict__ gmB,
                    OUTT* __restrict__ out, float* __restrict__ omax) {
    constexpr int KT = KD / 128;           // 8 (G1) / 32 (G2), even
    constexpr int NBC = ND / 128;
    __shared__ int8_t lA[2 * 128 * 128];   // 32 KB
    __shared__ int8_t lB[2 * 128 * 128];   // 32 KB
    const int t = threadIdx.x;
    const int lane = t & 63;
    const int w = t >> 6;
    const int wm = (w >> 1) * 64;
    const int wn = (w & 1) * 64;
    const int lr = lane & 15;
    const int lg = lane >> 4;

    // R7's XCD transform (measured FETCH-positive): bc fastest in logical order
    const int chunkX = gridDim.x >> 3;
    const int logical = (blockIdx.x & 7) * chunkX + (blockIdx.x >> 3);
    const int bc = logical % NBC;
    const int br = logical / NBC;

    const int8_t* Ab = A + (size_t)br * 128 * KD;
    const int8_t* Bb = B + (size_t)bc * 128 * KD;

    int32x4 acc[4][4] = {};
    int32x4 ra[4], rb[4];

// issue next tile's loads: linear lane->address, 1 KB coalesced per instr
#define LOADR(kt_) do {                                                           \
        _Pragma("unroll") for (int i_ = 0; i_ < 4; ++i_) {                        \
            int c_ = t + i_ * 256;                                                \
            ra[i_] = *(const int32x4*)(Ab + (size_t)(c_ >> 3) * KD + (kt_) * 128 + (c_ & 7) * 16); \
            rb[i_] = *(const int32x4*)(Bb + (size_t)(c_ >> 3) * KD + (kt_) * 128 + (c_ & 7) * 16); \
        } } while (0)

// write staged regs into buffer S at swizzled slots (read-compatible)
#define WRITE(S) do {                                                             \
        _Pragma("unroll") for (int i_ = 0; i_ < 4; ++i_) {                        \
            int c_ = t + i_ * 256;                                                \
            int r_ = c_ >> 3;                                                     \
            int d_ = r_ * 128 + (((c_ & 7) ^ (r_ & 7)) << 4);                     \
            *(int32x4*)&lA[(S) * 16384 + d_] = ra[i_];                            \
            *(int32x4*)&lB[(S) * 16384 + d_] = rb[i_];                            \
        } } while (0)

#define COMPUTE(S) do {                                                           \
        _Pragma("unroll") for (int kk = 0; kk < 2; ++kk) {                        \
            int32x4 af[4], bf[4];                                                 \
            _Pragma("unroll") for (int m = 0; m < 4; ++m) {                       \
                int r_ = wm + m * 16 + lr;                                        \
                int g_ = kk * 4 + lg;                                             \
                af[m] = *(const int32x4*)&lA[(S) * 16384 + r_ * 128 + ((g_ ^ (r_ & 7)) << 4)]; \
            }                                                                     \
            _Pragma("unroll") for (int n = 0; n < 4; ++n) {                       \
                int r_ = wn + n * 16 + lr;                                        \
                int g_ = kk * 4 + lg;                                             \
                bf[n] = *(const int32x4*)&lB[(S) * 16384 + r_ * 128 + ((g_ ^ (r_ & 7)) << 4)]; \
            }                                                                     \
            _Pragma("unroll") for (int m = 0; m < 4; ++m)                         \
                _Pragma("unroll") for (int n = 0; n < 4; ++n)                     \
                    acc[m][n] = __builtin_amdgcn_mfma_i32_16x16x64_i8(af[m], bf[n], acc[m][n], 0, 0, 0); \
        } } while (0)

    // prologue: tile0 -> regs -> buf0
    LOADR(0);
    WRITE(0);
    __syncthreads();

    for (int kt = 0; kt < KT; kt += 2) {
        if (kt + 1 < KT) LOADR(kt + 1);    // loads in flight...
        COMPUTE(0);                         // ...under this buffer's MFMA
        if (kt + 1 < KT) WRITE(1);          // vmcnt wait lands here (~elapsed)
        __syncthreads();
        if (kt + 2 < KT) LOADR(kt + 2);
        COMPUTE(1);
        if (kt + 2 < KT) WRITE(0);
        __syncthreads();
    }
#undef LOADR
#undef WRITE
#undef COMPUTE

    // epilogue — replicate reference fp32 op order exactly; absmax from the
    // full-precision fp32 value (scale semantics preserved for fp16 h out)
    const float sA = fmaxf(*gmA, MINR) / QP;
    const float sB = fmaxf(*gmB, MINR) / QP;
    const float s = sB * sA;
    float lmax = 0.0f;
    #pragma unroll
    for (int m = 0; m < 4; ++m) {
        #pragma unroll
        for (int n = 0; n < 4; ++n) {
            #pragma unroll
            for (int r = 0; r < 4; ++r) {
                int row = br * 128 + wm + m * 16 + lg * 4 + r;
                int col = bc * 128 + wn + n * 16 + lr;
                float f = (float)acc[m][n][r] + bias[col];
                f *= s;
                if (GELU_EPI) {
                    float gg = f * (erff(f / 1.41421356237309504880f) + 1.0f) * 0.5f;
                    out[(size_t)row * ND + col] = (OUTT)gg;
                    lmax = fmaxf(lmax, fabsf(gg));
                } else {
                    out[(size_t)row * ND + col] = (OUTT)f;
                }
            }
        }
    }
    if (GELU_EPI) {
        #pragma unroll
        for (int off = 32; off; off >>= 1) lmax = fmaxf(lmax, __shfl_down(lmax, off));
        __shared__ float red[4];
        if (lane == 0) red[w] = lmax;
        __syncthreads();
        if (t == 0) {
            float bm = fmaxf(fmaxf(red[0], red[1]), fmaxf(red[2], red[3]));
            atomicMax((int*)omax, __float_as_int(bm));
        }
    }
}

extern "C" void kernel_launch(void* const* d_in, const int* in_sizes, int n_in,
                              void* d_out, int out_size, void* d_ws, size_t ws_size,
                              hipStream_t stream) {
    const float* x  = (const float*)d_in[0];   // [8192, 1024]
    const float* w1 = (const float*)d_in[1];   // [4096, 1024]
    const float* b1 = (const float*)d_in[2];   // [4096]
    const float* w2 = (const float*)d_in[3];   // [1024, 4096]
    const float* b2 = (const float*)d_in[4];   // [1024]
    float* out = (float*)d_out;                // [8192, 1024]

    uint8_t* ws = (uint8_t*)d_ws;
    float*  gmax = (float*)ws;                           // [0]=x [1]=w1 [2]=h [3]=w2
    int8_t* xq   = (int8_t*)(ws + 256);                  // 8 MiB
    int8_t* w1q  = xq  + (size_t)MTOK * DDIM;            // 4 MiB
    int8_t* w2q  = w1q + (size_t)HDIM * DDIM;            // 4 MiB
    int8_t* hq   = w2q + (size_t)DDIM * HDIM;            // 32 MiB
    __half* h    = (__half*)(hq + (size_t)MTOK * HDIM);  // 64 MiB fp16

    zero_scales_kernel<<<1, 64, 0, stream>>>(gmax);

    absmax3_kernel<<<2048, 256, 0, stream>>>(x, w1, w2, gmax);
    quant3_kernel<<<4096, 256, 0, stream>>>(x, w1, w2, xq, w1q, w2q, gmax);

    // h(fp16) = gelu((xq @ w1q^T + b1) * s1), fused fp32 absmax(h) -> gmax[2]
    // grid = 2048 (%8==0)
    gemm_rs_kernel<DDIM, HDIM, true, __half>
        <<<2048, 256, 0, stream>>>(xq, w1q, b1, gmax + 0, gmax + 1, h, gmax + 2);

    quant_h_kernel<<<2048, 256, 0, stream>>>(h, hq, gmax + 2);

    // out = (hq @ w2q^T + b2) * s2 ; grid = 512 (%8==0)
    gemm_rs_kernel<HDIM, DDIM, false, float>
        <<<512, 256, 0, stream>>>(hq, w2q, b2, gmax + 2, gmax + 3, out, nullptr);
}

// Round 15
// 193.959 us; speedup vs baseline: 1.0939x; 1.0939x over previous
//
#include <hip/hip_runtime.h>
#include <hip/hip_fp16.h>
#include <cstdint>
#include <cmath>

#define QP    127.0f
#define MINR  1e-6f

// Problem dims: B*N = 8192 tokens, D = 1024, H = 4096
#define MTOK 8192
#define DDIM 1024
#define HDIM 4096

typedef __attribute__((ext_vector_type(4))) int int32x4;
typedef __attribute__((ext_vector_type(8))) short short8;

__device__ __forceinline__ void gload16(const void* g, void* l) {
    __builtin_amdgcn_global_load_lds(
        (const __attribute__((address_space(1))) void*)g,
        (__attribute__((address_space(3))) void*)l, 16, 0, 0);
}

__global__ void zero_scales_kernel(float* g) {
    if (threadIdx.x < 4) g[threadIdx.x] = 0.0f;
}

// ---- fused 3-tensor absmax: block-range partition, atomicMax per tensor ----
__device__ __forceinline__ float wave_block_max(float m) {
    #pragma unroll
    for (int off = 32; off; off >>= 1) m = fmaxf(m, __shfl_down(m, off));
    __shared__ float sm[4];
    int lane = threadIdx.x & 63, w = threadIdx.x >> 6;
    if (lane == 0) sm[w] = m;
    __syncthreads();
    float bm = 0.0f;
    if (threadIdx.x == 0) bm = fmaxf(fmaxf(sm[0], sm[1]), fmaxf(sm[2], sm[3]));
    return bm;
}

__device__ __forceinline__ void absmax_range(const float4* in4, int n4, int bid, int nb,
                                             float* gout) {
    int tid = bid * blockDim.x + threadIdx.x;
    int stride = nb * blockDim.x;
    float m = 0.0f;
    for (int i = tid; i < n4; i += stride) {
        float4 v = in4[i];
        m = fmaxf(m, fmaxf(fmaxf(fabsf(v.x), fabsf(v.y)), fmaxf(fabsf(v.z), fabsf(v.w))));
    }
    float bm = wave_block_max(m);
    if (threadIdx.x == 0) atomicMax((int*)gout, __float_as_int(bm));
}

// blocks [0,1024) -> x, [1024,1536) -> w1, [1536,2048) -> w2
__global__ void absmax3_kernel(const float* __restrict__ x, const float* __restrict__ w1,
                               const float* __restrict__ w2, float* __restrict__ gmax) {
    int b = blockIdx.x;
    if (b < 1024)      absmax_range((const float4*)x,  MTOK * DDIM / 4, b,        1024, gmax + 0);
    else if (b < 1536) absmax_range((const float4*)w1, HDIM * DDIM / 4, b - 1024,  512, gmax + 1);
    else               absmax_range((const float4*)w2, DDIM * HDIM / 4, b - 1536,  512, gmax + 3);
}

// ---------------------------------------------------------------------------
// K-tiled packed int8 layout: tensor [R][K] -> tiles [128 rows][128 B],
// tile (rt, kt) stored contiguously at ((rt*(K/128) + kt) << 14); inner byte
// (r&127)*128 + (k&127).  Each GEMM tile-step then stages one CONTIGUOUS
// 16 KB block per matrix (sequential streaming at wave/block/L2 granularity)
// instead of a strided column-slice (the one variable never isolated across
// R1-R14; m97's 14 TB/s vs our 6.1 TB/s fill anomaly).
// ---------------------------------------------------------------------------
__device__ __forceinline__ int pack4q(float4 v, float s) {
    return (((int)rintf(v.x / s)) & 255) | ((((int)rintf(v.y / s)) & 255) << 8) |
           ((((int)rintf(v.z / s)) & 255) << 16) | ((((int)rintf(v.w / s)) & 255) << 24);
}

// thread handles 16 output bytes = 16 floats at (r, k0); k0 % 16 == 0
template<int K>
__device__ __forceinline__ void quant_pack_range(const float* __restrict__ in,
                                                 int8_t* __restrict__ out, int R,
                                                 int bid, int nb,
                                                 const float* __restrict__ gm) {
    const float s = fmaxf(*gm, MINR) / QP;
    const float4* in4 = (const float4*)in;
    const int total = R * (K / 16);
    int tid = bid * blockDim.x + threadIdx.x;
    int stride = nb * blockDim.x;
    for (int i = tid; i < total; i += stride) {
        int ib = i << 4;
        int r  = ib / K;                 // K constexpr pow2 -> shift
        int k0 = ib & (K - 1);
        int32x4 q;
        q[0] = pack4q(in4[i * 4 + 0], s);
        q[1] = pack4q(in4[i * 4 + 1], s);
        q[2] = pack4q(in4[i * 4 + 2], s);
        q[3] = pack4q(in4[i * 4 + 3], s);
        size_t off = ((size_t)((r >> 7) * (K >> 7) + (k0 >> 7)) << 14)
                   + ((r & 127) << 7) + (k0 & 127);
        *(int32x4*)(out + off) = q;
    }
}

// blocks [0,2048) -> x, [2048,3072) -> w1, [3072,4096) -> w2
__global__ void quant3_kernel(const float* __restrict__ x, const float* __restrict__ w1,
                              const float* __restrict__ w2, int8_t* __restrict__ xq,
                              int8_t* __restrict__ w1q, int8_t* __restrict__ w2q,
                              const float* __restrict__ gmax) {
    int b = blockIdx.x;
    if (b < 2048)      quant_pack_range<DDIM>(x,  xq,  MTOK, b,        2048, gmax + 0);
    else if (b < 3072) quant_pack_range<DDIM>(w1, w1q, HDIM, b - 2048, 1024, gmax + 1);
    else               quant_pack_range<HDIM>(w2, w2q, DDIM, b - 3072, 1024, gmax + 3);
}

// quantize h (fp16, linear) -> packed int8.  8 halves/thread; k0 % 8 == 0.
__global__ void quant_h_kernel(const __half* __restrict__ h, int8_t* __restrict__ hq,
                               const float* __restrict__ gm) {
    const float s = fmaxf(*gm, MINR) / QP;
    const short8* in8 = (const short8*)h;
    const int n8 = MTOK * HDIM / 8;
    int tid = blockIdx.x * blockDim.x + threadIdx.x;
    int stride = gridDim.x * blockDim.x;
    for (int i = tid; i < n8; i += stride) {
        short8 v = in8[i];
        int q[8];
        #pragma unroll
        for (int j = 0; j < 8; ++j) {
            __half_raw r; r.x = (unsigned short)v[j];
            float f = __half2float(__half(r));
            q[j] = ((int)rintf(f / s)) & 255;
        }
        int2 o;
        o.x = q[0] | (q[1] << 8) | (q[2] << 16) | (q[3] << 24);
        o.y = q[4] | (q[5] << 8) | (q[6] << 16) | (q[7] << 24);
        int r  = i >> 9;                        // HDIM/8 = 512 chunks per row
        int k0 = (i & 511) << 3;
        size_t off = ((size_t)((r >> 7) * (HDIM >> 7) + (k0 >> 7)) << 14)
                   + ((r & 127) << 7) + (k0 & 127);
        *(int2*)(hq + off) = o;
    }
}

// ---------------------------------------------------------------------------
// Round-15 GEMM: R7's proven loop (measured 83.6-83.7 us, the floor across
// 11 structural variants) with ONE variable changed: A/B are K-tile-packed,
// so each tile-step stages a contiguous 16 KB block per matrix.  Source
// swizzle stays within the tile (wave still covers exactly its 1 KB, slots
// permuted -> coalescing unaffected); LDS image, XOR read swizzle, fragment
// math, and epilogue are byte-identical to R7.
// ---------------------------------------------------------------------------
template<int KD, int ND, bool GELU_EPI, typename OUTT>
__global__ __launch_bounds__(256, 2)
void gemm_i8_kernel(const int8_t* __restrict__ A, const int8_t* __restrict__ B,
                    const float* __restrict__ bias,
                    const float* __restrict__ gmA, const float* __restrict__ gmB,
                    OUTT* __restrict__ out, float* __restrict__ omax) {
    constexpr int KT = KD / 128;           // k-tiles per row-block
    constexpr int NBC = ND / 128;
    __shared__ int8_t lA[128 * 128];
    __shared__ int8_t lB[128 * 128];
    const int t = threadIdx.x;
    const int lane = t & 63;
    const int w = t >> 6;
    const int wm = (w >> 1) * 64;
    const int wn = (w & 1) * 64;
    const int lr = lane & 15;
    const int lg = lane >> 4;

    // R7's XCD transform (measured FETCH-positive): bc fastest in logical order
    const int chunk = gridDim.x >> 3;
    const int logical = (blockIdx.x & 7) * chunk + (blockIdx.x >> 3);
    const int bc = logical % NBC;
    const int br = logical / NBC;

    const int8_t* Ab = A + ((size_t)br * KT << 14);   // row-block's tile run
    const int8_t* Bb = B + ((size_t)bc * KT << 14);

    int32x4 acc[4][4] = {};

    for (int kt = 0; kt < KT; ++kt) {
        // stage one contiguous 16 KB tile per matrix; slot pre-swizzled
        // within the tile (involution matches the read side)
        #pragma unroll
        for (int i = 0; i < 4; ++i) {
            int c = t + i * 256;          // 0..1023
            int r = c >> 3;               // tile row 0..127
            int sl = c & 7;               // 16B slot
            int src = r * 128 + ((sl ^ (r & 7)) << 4);
            gload16(Ab + ((size_t)kt << 14) + src, &lA[c * 16]);
            gload16(Bb + ((size_t)kt << 14) + src, &lB[c * 16]);
        }
        __syncthreads();

        #pragma unroll
        for (int kk = 0; kk < 2; ++kk) {
            int32x4 af[4], bf[4];
            #pragma unroll
            for (int m = 0; m < 4; ++m) {
                int r = wm + m * 16 + lr;
                int g = kk * 4 + lg;
                af[m] = *(const int32x4*)&lA[r * 128 + ((g ^ (r & 7)) << 4)];
            }
            #pragma unroll
            for (int n = 0; n < 4; ++n) {
                int r = wn + n * 16 + lr;
                int g = kk * 4 + lg;
                bf[n] = *(const int32x4*)&lB[r * 128 + ((g ^ (r & 7)) << 4)];
            }
            #pragma unroll
            for (int m = 0; m < 4; ++m)
                #pragma unroll
                for (int n = 0; n < 4; ++n)
                    acc[m][n] = __builtin_amdgcn_mfma_i32_16x16x64_i8(af[m], bf[n], acc[m][n], 0, 0, 0);
        }
        __syncthreads();
    }

    // epilogue — replicate reference fp32 op order exactly; absmax from the
    // full-precision fp32 value (scale semantics preserved for fp16 h out)
    const float sA = fmaxf(*gmA, MINR) / QP;
    const float sB = fmaxf(*gmB, MINR) / QP;
    const float s = sB * sA;
    float lmax = 0.0f;
    #pragma unroll
    for (int m = 0; m < 4; ++m) {
        #pragma unroll
        for (int n = 0; n < 4; ++n) {
            #pragma unroll
            for (int r = 0; r < 4; ++r) {
                int row = br * 128 + wm + m * 16 + lg * 4 + r;
                int col = bc * 128 + wn + n * 16 + lr;
                float f = (float)acc[m][n][r] + bias[col];
                f *= s;
                if (GELU_EPI) {
                    float gg = f * (erff(f / 1.41421356237309504880f) + 1.0f) * 0.5f;
                    out[(size_t)row * ND + col] = (OUTT)gg;
                    lmax = fmaxf(lmax, fabsf(gg));
                } else {
                    out[(size_t)row * ND + col] = (OUTT)f;
                }
            }
        }
    }
    if (GELU_EPI) {
        #pragma unroll
        for (int off = 32; off; off >>= 1) lmax = fmaxf(lmax, __shfl_down(lmax, off));
        __shared__ float red[4];
        if (lane == 0) red[w] = lmax;
        __syncthreads();
        if (t == 0) {
            float bm = fmaxf(fmaxf(red[0], red[1]), fmaxf(red[2], red[3]));
            atomicMax((int*)omax, __float_as_int(bm));
        }
    }
}

extern "C" void kernel_launch(void* const* d_in, const int* in_sizes, int n_in,
                              void* d_out, int out_size, void* d_ws, size_t ws_size,
                              hipStream_t stream) {
    const float* x  = (const float*)d_in[0];   // [8192, 1024]
    const float* w1 = (const float*)d_in[1];   // [4096, 1024]
    const float* b1 = (const float*)d_in[2];   // [4096]
    const float* w2 = (const float*)d_in[3];   // [1024, 4096]
    const float* b2 = (const float*)d_in[4];   // [1024]
    float* out = (float*)d_out;                // [8192, 1024]

    uint8_t* ws = (uint8_t*)d_ws;
    float*  gmax = (float*)ws;                           // [0]=x [1]=w1 [2]=h [3]=w2
    int8_t* xq   = (int8_t*)(ws + 256);                  // 8 MiB, packed
    int8_t* w1q  = xq  + (size_t)MTOK * DDIM;            // 4 MiB, packed
    int8_t* w2q  = w1q + (size_t)HDIM * DDIM;            // 4 MiB, packed
    int8_t* hq   = w2q + (size_t)DDIM * HDIM;            // 32 MiB, packed
    __half* h    = (__half*)(hq + (size_t)MTOK * HDIM);  // 64 MiB fp16, linear

    zero_scales_kernel<<<1, 64, 0, stream>>>(gmax);

    absmax3_kernel<<<2048, 256, 0, stream>>>(x, w1, w2, gmax);
    quant3_kernel<<<4096, 256, 0, stream>>>(x, w1, w2, xq, w1q, w2q, gmax);

    // h(fp16) = gelu((xq @ w1q^T + b1) * s1), fused fp32 absmax(h) -> gmax[2]
    // grid = 2048 (%8==0)
    gemm_i8_kernel<DDIM, HDIM, true, __half>
        <<<2048, 256, 0, stream>>>(xq, w1q, b1, gmax + 0, gmax + 1, h, gmax + 2);

    quant_h_kernel<<<2048, 256, 0, stream>>>(h, hq, gmax + 2);

    // out = (hq @ w2q^T + b2) * s2 ; grid = 512 (%8==0)
    gemm_i8_kernel<HDIM, DDIM, false, float>
        <<<512, 256, 0, stream>>>(hq, w2q, b2, gmax + 2, gmax + 3, out, nullptr);
}